// Round 1
// baseline (231.180 us; speedup 1.0000x reference)
//
#include <hip/hip_runtime.h>

#define NB 64
#define NN 100
#define DL 32
#define BN (NB * NN)  // 6400

typedef short short8 __attribute__((ext_vector_type(8)));
typedef float f32x4 __attribute__((ext_vector_type(4)));

static __device__ __forceinline__ unsigned short f2bf(float f) {
    unsigned int u = __float_as_uint(f);
    unsigned int r = (u + 0x7fffu + ((u >> 16) & 1u)) >> 16;
    return (unsigned short)r;
}
static __device__ __forceinline__ float bf2f(unsigned short s) {
    return __uint_as_float(((unsigned int)s) << 16);
}
static __device__ __forceinline__ float lrelu(float x) { return fmaxf(x, 0.1f * x); }

// h = x @ lin_w + lin_b   (64x32 @ 32x3200)
__global__ void k_lin(const float* __restrict__ x, const float* __restrict__ w,
                      const float* __restrict__ b, float* __restrict__ h) {
    int t = blockIdx.x * 256 + threadIdx.x;
    if (t >= NB * 3200) return;
    int m = t % 3200, bb = t / 3200;
    const float* xr = x + bb * DL;
    float s = b[m];
#pragma unroll
    for (int c = 0; c < DL; ++c) s += xr[c] * w[c * 3200 + m];
    h[t] = s;
}

// U = h @ W0[0:32] + b0 ; V = h @ W0[32:64]
__global__ void k_uv(const float* __restrict__ h, const float* __restrict__ w0,
                     const float* __restrict__ b0, float* __restrict__ U,
                     float* __restrict__ V) {
    int t = blockIdx.x * 256 + threadIdx.x;
    if (t >= BN * 128) return;
    int k = t & 63;
    int which = (t >> 6) & 1;
    int n = t >> 7;
    const float* hr = h + n * DL;
    const float* w = w0 + (which ? DL * 64 : 0) + k;
    float s = which ? 0.0f : b0[k];
#pragma unroll
    for (int c = 0; c < DL; ++c) s += hr[c] * w[c * 64];
    if (which) V[n * 64 + k] = s;
    else       U[n * 64 + k] = s;
}

// Fused edge MLP + aggregation over j. One block per (b,i); 4 waves, wave w owns
// k in [16w,16w+16). j tiled by 16 (7 tiles, tail masked). Split-bf16 x3 MFMA.
__global__ __launch_bounds__(256, 2) void k_edge(
    const float* __restrict__ h, const float* __restrict__ U, const float* __restrict__ V,
    const float* __restrict__ w0, const float* __restrict__ w1, const float* __restrict__ b1,
    float* __restrict__ agg) {
    __shared__ float dist[112];
    __shared__ unsigned short Phi[16][72];  // +8 shorts row pad: conflict-light b128 reads
    __shared__ unsigned short Plo[16][72];

    int bi = blockIdx.x;
    int b = bi / NN;
    int t = threadIdx.x;

    // distances dist[i, j] for all j (clamped beyond 99; masked in epilogue)
    if (t < 112) {
        int j = t < NN ? t : NN - 1;
        const float4* hi4 = (const float4*)(h + bi * DL);
        const float4* hj4 = (const float4*)(h + (b * NN + j) * DL);
        float s = 0.f;
#pragma unroll
        for (int r = 0; r < 8; ++r) {
            float4 a = hi4[r], c = hj4[r];
            float d0 = a.x - c.x, d1 = a.y - c.y, d2 = a.z - c.z, d3 = a.w - c.w;
            s += d0 * d0 + d1 * d1 + d2 * d2 + d3 * d3;
        }
        dist[t] = sqrtf(s + 1e-12f);
    }

    // P-build invariants: thread handles row bj, columns c0..c0+3
    int bj = t & 15;
    int c0 = (t >> 4) * 4;
    float4 uv = *(const float4*)(U + bi * 64 + c0);          // U_i + b0 folded
    float4 wd = *(const float4*)(w0 + 64 * 64 + c0);         // dist row of W0

    // MFMA invariants
    int w = t >> 6;
    int lane = t & 63;
    int q = lane >> 4;
    int kk = lane & 15;
    int k = w * 16 + kk;
    float b1k = b1[k];

    // B fragments: W1 split hi/lo, both K-halves, for this wave's k-tile
    short8 Bhi0, Bhi1, Blo0, Blo1;
#pragma unroll
    for (int jj = 0; jj < 8; ++jj) {
        int c = q * 8 + jj;
        float wv = w1[c * 64 + k];
        unsigned short hb = f2bf(wv);
        Bhi0[jj] = (short)hb;
        Blo0[jj] = (short)f2bf(wv - bf2f(hb));
        wv = w1[(c + 32) * 64 + k];
        hb = f2bf(wv);
        Bhi1[jj] = (short)hb;
        Blo1[jj] = (short)f2bf(wv - bf2f(hb));
    }

    float s_agg = 0.f;
    __syncthreads();

    for (int jt = 0; jt < 7; ++jt) {
        {  // build P tile (leaky(U_i + V_j + dist*wd)) in split bf16
            int jg = jt * 16 + bj;
            int jc = jg < NN ? jg : NN - 1;
            float dj = dist[jg];
            float4 v = *(const float4*)(V + (b * NN + jc) * 64 + c0);
            float p0 = lrelu(uv.x + v.x + dj * wd.x);
            float p1 = lrelu(uv.y + v.y + dj * wd.y);
            float p2 = lrelu(uv.z + v.z + dj * wd.z);
            float p3 = lrelu(uv.w + v.w + dj * wd.w);
            unsigned short h0 = f2bf(p0), h1 = f2bf(p1), h2 = f2bf(p2), h3 = f2bf(p3);
            ushort4 hiv = make_ushort4(h0, h1, h2, h3);
            ushort4 lov = make_ushort4(f2bf(p0 - bf2f(h0)), f2bf(p1 - bf2f(h1)),
                                       f2bf(p2 - bf2f(h2)), f2bf(p3 - bf2f(h3)));
            *(ushort4*)&Phi[bj][c0] = hiv;
            *(ushort4*)&Plo[bj][c0] = lov;
        }
        __syncthreads();

        short8 Ahi0 = *(const short8*)&Phi[kk][q * 8];
        short8 Ahi1 = *(const short8*)&Phi[kk][32 + q * 8];
        short8 Alo0 = *(const short8*)&Plo[kk][q * 8];
        short8 Alo1 = *(const short8*)&Plo[kk][32 + q * 8];

        f32x4 acc = {0.f, 0.f, 0.f, 0.f};
        acc = __builtin_amdgcn_mfma_f32_16x16x32_bf16(Ahi0, Bhi0, acc, 0, 0, 0);
        acc = __builtin_amdgcn_mfma_f32_16x16x32_bf16(Ahi1, Bhi1, acc, 0, 0, 0);
        acc = __builtin_amdgcn_mfma_f32_16x16x32_bf16(Ahi0, Blo0, acc, 0, 0, 0);
        acc = __builtin_amdgcn_mfma_f32_16x16x32_bf16(Ahi1, Blo1, acc, 0, 0, 0);
        acc = __builtin_amdgcn_mfma_f32_16x16x32_bf16(Alo0, Bhi0, acc, 0, 0, 0);
        acc = __builtin_amdgcn_mfma_f32_16x16x32_bf16(Alo1, Bhi1, acc, 0, 0, 0);

#pragma unroll
        for (int r = 0; r < 4; ++r) {
            int jrow = jt * 16 + q * 4 + r;  // C/D: row = quad*4 + reg
            float y = acc[r] + b1k;
            float a = lrelu(y);
            s_agg += (jrow < NN) ? a : 0.f;
        }
        __syncthreads();
    }

    s_agg += __shfl_xor(s_agg, 16);
    s_agg += __shfl_xor(s_agg, 32);
    if (lane < 16) agg[bi * 64 + k] = s_agg;
}

// t0 = leaky([h, agg] @ nw0 + nb0)
__global__ void k_node0(const float* __restrict__ h, const float* __restrict__ agg,
                        const float* __restrict__ w, const float* __restrict__ b,
                        float* __restrict__ t0) {
    int t = blockIdx.x * 256 + threadIdx.x;
    if (t >= BN * 64) return;
    int k = t & 63, n = t >> 6;
    float s = b[k];
    const float* hr = h + n * DL;
    const float* ar = agg + n * 64;
#pragma unroll
    for (int c = 0; c < DL; ++c) s += hr[c] * w[c * 64 + k];
#pragma unroll
    for (int c = 0; c < 64; ++c) s += ar[c] * w[(DL + c) * 64 + k];
    t0[t] = lrelu(s);
}

// h = leaky(t0 @ nw1 + nb1)
__global__ void k_node1(const float* __restrict__ t0, const float* __restrict__ w,
                        const float* __restrict__ b, float* __restrict__ h) {
    int t = blockIdx.x * 256 + threadIdx.x;
    if (t >= BN * DL) return;
    int k = t & 31, n = t >> 5;
    float s = b[k];
    const float* tr = t0 + n * 64;
#pragma unroll
    for (int c = 0; c < 64; ++c) s += tr[c] * w[c * DL + k];
    h[t] = lrelu(s);
}

// out = tanh(h @ out_w + out_b)
__global__ void k_out(const float* __restrict__ h, const float* __restrict__ w,
                      const float* __restrict__ b, float* __restrict__ out) {
    int t = blockIdx.x * 256 + threadIdx.x;
    if (t >= BN * 3) return;
    int o = t % 3, n = t / 3;
    float s = b[o];
    const float* hr = h + n * DL;
#pragma unroll
    for (int c = 0; c < DL; ++c) s += hr[c] * w[c * 3 + o];
    out[t] = tanhf(s);
}

extern "C" void kernel_launch(void* const* d_in, const int* in_sizes, int n_in,
                              void* d_out, int out_size, void* d_ws, size_t ws_size,
                              hipStream_t stream) {
    const float* x     = (const float*)d_in[0];
    const float* lin_w = (const float*)d_in[1];
    const float* lin_b = (const float*)d_in[2];
    const float* ew0[2] = {(const float*)d_in[3],  (const float*)d_in[11]};
    const float* eb0[2] = {(const float*)d_in[4],  (const float*)d_in[12]};
    const float* ew1[2] = {(const float*)d_in[5],  (const float*)d_in[13]};
    const float* eb1[2] = {(const float*)d_in[6],  (const float*)d_in[14]};
    const float* nw0[2] = {(const float*)d_in[7],  (const float*)d_in[15]};
    const float* nb0[2] = {(const float*)d_in[8],  (const float*)d_in[16]};
    const float* nw1[2] = {(const float*)d_in[9],  (const float*)d_in[17]};
    const float* nb1[2] = {(const float*)d_in[10], (const float*)d_in[18]};
    const float* ow = (const float*)d_in[19];
    const float* ob = (const float*)d_in[20];
    float* out = (float*)d_out;

    float* h   = (float*)d_ws;            // 6400 x 32
    float* U   = h + 204800;              // 6400 x 64
    float* V   = U + 409600;              // 6400 x 64
    float* agg = V + 409600;              // 6400 x 64
    float* t0  = agg + 409600;            // 6400 x 64

    k_lin<<<800, 256, 0, stream>>>(x, lin_w, lin_b, h);
    for (int s = 0; s < 2; ++s) {
        k_uv<<<3200, 256, 0, stream>>>(h, ew0[s], eb0[s], U, V);
        k_edge<<<6400, 256, 0, stream>>>(h, U, V, ew0[s], ew1[s], eb1[s], agg);
        k_node0<<<1600, 256, 0, stream>>>(h, agg, nw0[s], nb0[s], t0);
        k_node1<<<800, 256, 0, stream>>>(t0, nw1[s], nb1[s], h);
    }
    k_out<<<75, 256, 0, stream>>>(h, ow, ob, out);
}